// Round 3
// 200.137 us; speedup vs baseline: 1.0013x; 1.0013x over previous
//
#include <hip/hip_runtime.h>

#define N_NODES 20000
#define N_EDGES 320000
#define IN_F    168
#define HID     256
#define K1P     192   // GEMM-1 K (IN_F zero-padded to multiple of 64)
#define XS      192   // xb row stride in shorts (384B, 128B-aligned)
#define NF4     42    // IN_F / 4
#define X4      48    // K1P / 4 (short4 per padded row)

typedef __attribute__((ext_vector_type(8))) short bf16x8;
typedef __attribute__((ext_vector_type(4))) float f32x4;
typedef __attribute__((ext_vector_type(2))) float f32x2;

__device__ __forceinline__ short f2bf(float f) {
    union { float f; unsigned u; } v; v.f = f;
    unsigned r = v.u + 0x7FFFu + ((v.u >> 16) & 1u);
    return (short)(r >> 16);
}
// unpack 2 bf16 packed in a dword -> 2 fp32 (lo short -> .x, hi short -> .y)
__device__ __forceinline__ f32x2 bfp(unsigned u) {
    f32x2 r;
    r.x = __uint_as_float(u << 16);
    r.y = __uint_as_float(u & 0xFFFF0000u);
    return r;
}

// ---------------- fused prep: x->bf16 (192-padded), W->bf16, edge deg/count ----
// flattened grid over: x float4s | W1 float4s | W2 float4s | edges
__global__ void prep_all(const float* __restrict__ x, short* __restrict__ xb,
                         const float* __restrict__ W1, const float* __restrict__ W2,
                         short* __restrict__ w1b, short* __restrict__ w2b,
                         const int* __restrict__ ei, const float* __restrict__ ew,
                         float* __restrict__ deg, int* __restrict__ counts) {
    const int xTot  = N_NODES * X4;   // 960000
    const int w1Tot = 256 * X4;       // 12288
    const int w2Tot = 256 * 64;       // 16384
    int i = blockIdx.x * 256 + threadIdx.x;
    if (i < xTot) {
        int n  = i / X4;
        int k4 = i - n * X4;
        short4 o;
        if (k4 < NF4) {
            float4 v = *(const float4*)(x + (size_t)n * IN_F + k4 * 4);
            o = make_short4(f2bf(v.x), f2bf(v.y), f2bf(v.z), f2bf(v.w));
        } else {
            o = make_short4(0, 0, 0, 0);
        }
        *(short4*)(xb + (size_t)n * XS + k4 * 4) = o;
        return;
    }
    i -= xTot;
    if (i < w1Tot) {
        int r  = i / X4;
        int k4 = i - r * X4;
        short4 o;
        if (k4 < NF4) {
            float4 v = *(const float4*)(W1 + (size_t)r * IN_F + k4 * 4);
            o = make_short4(f2bf(v.x), f2bf(v.y), f2bf(v.z), f2bf(v.w));
        } else {
            o = make_short4(0, 0, 0, 0);
        }
        *(short4*)(w1b + (size_t)r * K1P + k4 * 4) = o;
        return;
    }
    i -= w1Tot;
    if (i < w2Tot) {
        int r  = i >> 6;
        int c4 = i & 63;
        float4 v = *(const float4*)(W2 + (size_t)r * HID + c4 * 4);
        *(short4*)(w2b + (size_t)r * HID + c4 * 4) =
            make_short4(f2bf(v.x), f2bf(v.y), f2bf(v.z), f2bf(v.w));
        return;
    }
    i -= w2Tot;
    if (i < N_EDGES) {
        int d = ei[N_EDGES + i];
        atomicAdd(&deg[d], ew[i]);
        atomicAdd(&counts[d], 1);
    }
}

// ---------------- scan (2-kernel) + scatter ----------------
// scans counts padded to multiples of 8 -> all bucket starts 8-record aligned

__global__ __launch_bounds__(1024) void scan_part(const int* __restrict__ counts,
                                                  int* __restrict__ offs,
                                                  int* __restrict__ bsum,
                                                  float* __restrict__ deg, int n) {
    int tid  = threadIdx.x;
    int lane = tid & 63;
    int wv   = tid >> 6;
    int i = blockIdx.x * 1024 + tid;
    if (i < n) deg[i] = rsqrtf(deg[i] + 1.0f);     // self-loop weight 1.0
    __shared__ int wsum[16];
    int v = (i < n) ? ((counts[i] + 7) & ~7) : 0;  // pad bucket to 8 records
    int incl = v;
    #pragma unroll
    for (int d = 1; d < 64; d <<= 1) {
        int t = __shfl_up(incl, d);
        if (lane >= d) incl += t;
    }
    if (lane == 63) wsum[wv] = incl;
    __syncthreads();
    if (wv == 0) {
        int w = (lane < 16) ? wsum[lane] : 0;
        int winc = w;
        #pragma unroll
        for (int d = 1; d < 16; d <<= 1) {
            int t = __shfl_up(winc, d);
            if (lane >= d) winc += t;
        }
        if (lane < 16) wsum[lane] = winc - w;
    }
    __syncthreads();
    if (i < n) offs[i] = wsum[wv] + incl - v;
    if (tid == 1023) bsum[blockIdx.x] = wsum[15] + incl;
}

__global__ __launch_bounds__(1024) void scan_add(const int* __restrict__ bsum,
                                                 int* __restrict__ offs, int n) {
    int i = blockIdx.x * 1024 + threadIdx.x;
    int add = 0;
    for (int b = 0; b < (int)blockIdx.x; ++b) add += bsum[b];
    if (i < n) offs[i] += add;
    if (i == n) offs[n] = add + bsum[blockIdx.x];
}

// packed edge record: .x = src node, .y = norm as float bits.
// blocks [0, EB): scatter edges; blocks [EB, EB+NB): explicitly zero-fill the
// pad slots [offs[n]+counts[n], offs[n+1]) so er is fully deterministic
// without any large memset (pad slots: src=0, w=0.0 -> exact no-op in agg).
__global__ void scatter_edges(const int* __restrict__ ei, const float* __restrict__ ew,
                              const float* __restrict__ dinv, const int* __restrict__ offs,
                              const int* __restrict__ counts,
                              int* __restrict__ cursor, int2* __restrict__ er) {
    int t = blockIdx.x * 256 + threadIdx.x;
    if (t < N_EDGES) {
        int s = ei[t];
        int d = ei[N_EDGES + t];
        int pos = offs[d] + atomicAdd(&cursor[d], 1);
        float nm = dinv[s] * ew[t] * dinv[d];
        er[pos] = make_int2(s, __float_as_int(nm));
        return;
    }
    int n = t - N_EDGES;
    if (n < N_NODES) {
        int p   = offs[n] + counts[n];
        int end = offs[n + 1];
        for (; p < end; ++p) er[p] = make_int2(0, 0);
    }
}

// ---------------- gathers (Agg BEFORE GEMM; emit bf16 A operand) ----------------
// buckets 8-padded: single full-batch loop, int4 er loads, packed f32x2 FMA.

// layer 1: agg from bf16 xb rows (384B stride); lanes 0..41 own short4.
__global__ __launch_bounds__(256) void agg_x(const short* __restrict__ xb,
                                             const float* __restrict__ dinv,
                                             const int* __restrict__ offs,
                                             const int2* __restrict__ er,
                                             short* __restrict__ ax) {
    int wave = threadIdx.x >> 6;
    int lane = threadIdx.x & 63;
    int n = blockIdx.x * 4 + wave;
    bool act = lane < NF4;
    int lo4 = act ? lane * 4 : 0;                  // inactive lanes read row start (safe)
    float di = dinv[n];
    float sw = di * di;
    uint2 sv = *(const uint2*)(xb + (size_t)n * XS + lo4);
    f32x2 a01 = bfp(sv.x) * sw;
    f32x2 a23 = bfp(sv.y) * sw;

    int p0 = offs[n], p1 = offs[n + 1];            // both multiples of 8
    for (int p = p0; p < p1; p += 8) {
        const int4* e4 = (const int4*)(er + p);    // 16B-aligned
        int4 eA = e4[0], eB = e4[1], eC = e4[2], eD = e4[3];
        uint2 r0 = *(const uint2*)(xb + (size_t)eA.x * XS + lo4);
        uint2 r1 = *(const uint2*)(xb + (size_t)eA.z * XS + lo4);
        uint2 r2 = *(const uint2*)(xb + (size_t)eB.x * XS + lo4);
        uint2 r3 = *(const uint2*)(xb + (size_t)eB.z * XS + lo4);
        uint2 r4 = *(const uint2*)(xb + (size_t)eC.x * XS + lo4);
        uint2 r5 = *(const uint2*)(xb + (size_t)eC.z * XS + lo4);
        uint2 r6 = *(const uint2*)(xb + (size_t)eD.x * XS + lo4);
        uint2 r7 = *(const uint2*)(xb + (size_t)eD.z * XS + lo4);
        float w0 = __int_as_float(eA.y), w1 = __int_as_float(eA.w);
        float w2 = __int_as_float(eB.y), w3 = __int_as_float(eB.w);
        float w4 = __int_as_float(eC.y), w5 = __int_as_float(eC.w);
        float w6 = __int_as_float(eD.y), w7 = __int_as_float(eD.w);
        a01 += bfp(r0.x) * w0; a23 += bfp(r0.y) * w0;
        a01 += bfp(r1.x) * w1; a23 += bfp(r1.y) * w1;
        a01 += bfp(r2.x) * w2; a23 += bfp(r2.y) * w2;
        a01 += bfp(r3.x) * w3; a23 += bfp(r3.y) * w3;
        a01 += bfp(r4.x) * w4; a23 += bfp(r4.y) * w4;
        a01 += bfp(r5.x) * w5; a23 += bfp(r5.y) * w5;
        a01 += bfp(r6.x) * w6; a23 += bfp(r6.y) * w6;
        a01 += bfp(r7.x) * w7; a23 += bfp(r7.y) * w7;
    }

    size_t base = (size_t)n * K1P + lane * 4;
    if (act) {
        *(short4*)&ax[base] = make_short4(f2bf(a01.x), f2bf(a01.y),
                                          f2bf(a23.x), f2bf(a23.y));
    } else if (lane < 48) {                        // zero pad cols 168..191
        *(short4*)&ax[base] = make_short4(0, 0, 0, 0);
    }
}

// layer 2: agg from bf16 h1 rows (512B); one short4 per lane.
__global__ __launch_bounds__(256) void agg_h(const short* __restrict__ h1h,
                                             const float* __restrict__ dinv,
                                             const int* __restrict__ offs,
                                             const int2* __restrict__ er,
                                             short* __restrict__ ah) {
    int wave = threadIdx.x >> 6;
    int lane = threadIdx.x & 63;
    int n = blockIdx.x * 4 + wave;
    int lo4 = lane * 4;
    float di = dinv[n];
    float sw = di * di;
    uint2 sv = *(const uint2*)(h1h + (size_t)n * HID + lo4);
    f32x2 a01 = bfp(sv.x) * sw;
    f32x2 a23 = bfp(sv.y) * sw;

    int p0 = offs[n], p1 = offs[n + 1];
    for (int p = p0; p < p1; p += 8) {
        const int4* e4 = (const int4*)(er + p);
        int4 eA = e4[0], eB = e4[1], eC = e4[2], eD = e4[3];
        uint2 r0 = *(const uint2*)(h1h + (size_t)eA.x * HID + lo4);
        uint2 r1 = *(const uint2*)(h1h + (size_t)eA.z * HID + lo4);
        uint2 r2 = *(const uint2*)(h1h + (size_t)eB.x * HID + lo4);
        uint2 r3 = *(const uint2*)(h1h + (size_t)eB.z * HID + lo4);
        uint2 r4 = *(const uint2*)(h1h + (size_t)eC.x * HID + lo4);
        uint2 r5 = *(const uint2*)(h1h + (size_t)eC.z * HID + lo4);
        uint2 r6 = *(const uint2*)(h1h + (size_t)eD.x * HID + lo4);
        uint2 r7 = *(const uint2*)(h1h + (size_t)eD.z * HID + lo4);
        float w0 = __int_as_float(eA.y), w1 = __int_as_float(eA.w);
        float w2 = __int_as_float(eB.y), w3 = __int_as_float(eB.w);
        float w4 = __int_as_float(eC.y), w5 = __int_as_float(eC.w);
        float w6 = __int_as_float(eD.y), w7 = __int_as_float(eD.w);
        a01 += bfp(r0.x) * w0; a23 += bfp(r0.y) * w0;
        a01 += bfp(r1.x) * w1; a23 += bfp(r1.y) * w1;
        a01 += bfp(r2.x) * w2; a23 += bfp(r2.y) * w2;
        a01 += bfp(r3.x) * w3; a23 += bfp(r3.y) * w3;
        a01 += bfp(r4.x) * w4; a23 += bfp(r4.y) * w4;
        a01 += bfp(r5.x) * w5; a23 += bfp(r5.y) * w5;
        a01 += bfp(r6.x) * w6; a23 += bfp(r6.y) * w6;
        a01 += bfp(r7.x) * w7; a23 += bfp(r7.y) * w7;
    }

    *(short4*)&ah[(size_t)n * HID + lo4] = make_short4(f2bf(a01.x), f2bf(a01.y),
                                                       f2bf(a23.x), f2bf(a23.y));
}

// ---------------- MFMA GEMM (pure bf16) with fused bias+ReLU epilogue ----------
// C[M,256] = relu(A[M,K] * W[256,K]^T + bias), A and W bf16 (RNE), fp32 MFMA acc.
// 64x64 tile, 4 waves each 32x32 (2x2 MFMA 16x16x32), BK=64, LDS-staged,
// register prefetch, XCD-affinity swizzle. mode 0: bf16 out; mode 1: fp32 out.

#define LDS_STRIDE 72

__global__ __launch_bounds__(256) void gemm_bf(const short* __restrict__ Ah,
                                               const short* __restrict__ Wh,
                                               const float* __restrict__ bias,
                                               float* __restrict__ Cf,
                                               short* __restrict__ Cbf,
                                               int M, int Ks, int nsteps, int mode) {
    __shared__ short sAh[64 * LDS_STRIDE];
    __shared__ short sWh[64 * LDS_STRIDE];

    const int idx   = blockIdx.x;
    const int group = idx >> 5;
    const int xcd   = idx & 7;
    const int slot  = (idx >> 3) & 3;
    const int mt    = group * 8 + xcd;
    const int mtiles = (M + 63) >> 6;
    if (mt >= mtiles) return;
    const int bm = mt * 64;
    const int bn = slot * 64;

    const int tid  = threadIdx.x;
    const int lane = tid & 63;
    const int wv   = tid >> 6;
    const int l16  = lane & 15;
    const int quad = lane >> 4;
    const int wm   = (wv & 1) * 32;
    const int wn   = (wv >> 1) * 32;

    const int srow = tid >> 2;
    const int sseg = (tid & 3) * 16;
    int arow = bm + srow; if (arow >= M) arow = M - 1;
    const short* gAh = Ah + (size_t)arow * Ks;
    const short* gWh = Wh + (size_t)(bn + srow) * Ks;
    const int lds_off = srow * LDS_STRIDE + sseg;

    f32x4 acc00 = {0,0,0,0}, acc01 = {0,0,0,0}, acc10 = {0,0,0,0}, acc11 = {0,0,0,0};

    int4 pah0 = *(const int4*)(gAh + sseg), pah1 = *(const int4*)(gAh + sseg + 8);
    int4 pwh0 = *(const int4*)(gWh + sseg), pwh1 = *(const int4*)(gWh + sseg + 8);

    for (int ks = 0; ks < nsteps; ++ks) {
        *(int4*)&sAh[lds_off] = pah0; *(int4*)&sAh[lds_off + 8] = pah1;
        *(int4*)&sWh[lds_off] = pwh0; *(int4*)&sWh[lds_off + 8] = pwh1;
        __syncthreads();
        if (ks + 1 < nsteps) {
            int o = (ks + 1) * 64 + sseg;
            pah0 = *(const int4*)(gAh + o); pah1 = *(const int4*)(gAh + o + 8);
            pwh0 = *(const int4*)(gWh + o); pwh1 = *(const int4*)(gWh + o + 8);
        }
        #pragma unroll
        for (int o = 0; o < 2; ++o) {
            const int a0 = (wm + l16) * LDS_STRIDE + o * 32 + quad * 8;
            const int a1 = a0 + 16 * LDS_STRIDE;
            const int w0 = (wn + l16) * LDS_STRIDE + o * 32 + quad * 8;
            const int w1 = w0 + 16 * LDS_STRIDE;
            bf16x8 ah0 = *(const bf16x8*)&sAh[a0];
            bf16x8 ah1 = *(const bf16x8*)&sAh[a1];
            bf16x8 wh0 = *(const bf16x8*)&sWh[w0];
            bf16x8 wh1 = *(const bf16x8*)&sWh[w1];
            acc00 = __builtin_amdgcn_mfma_f32_16x16x32_bf16(ah0, wh0, acc00, 0, 0, 0);
            acc01 = __builtin_amdgcn_mfma_f32_16x16x32_bf16(ah0, wh1, acc01, 0, 0, 0);
            acc10 = __builtin_amdgcn_mfma_f32_16x16x32_bf16(ah1, wh0, acc10, 0, 0, 0);
            acc11 = __builtin_amdgcn_mfma_f32_16x16x32_bf16(ah1, wh1, acc11, 0, 0, 0);
        }
        __syncthreads();
    }

    const int colb = bn + wn + l16;
    const int rowb = bm + wm + quad * 4;
    const float b0 = bias[colb];
    const float b1 = bias[colb + 16];
    #pragma unroll
    for (int r = 0; r < 4; ++r) {
        int row = rowb + r;
        if (row < M) {
            float v0 = acc00[r] + b0; v0 = v0 > 0.f ? v0 : 0.f;
            float v1 = acc01[r] + b1; v1 = v1 > 0.f ? v1 : 0.f;
            if (mode == 0) {
                Cbf[(size_t)row * HID + colb]      = f2bf(v0);
                Cbf[(size_t)row * HID + colb + 16] = f2bf(v1);
            } else {
                Cf[(size_t)row * HID + colb]      = v0;
                Cf[(size_t)row * HID + colb + 16] = v1;
            }
        }
        int row2 = row + 16;
        if (row2 < M) {
            float v0 = acc10[r] + b0; v0 = v0 > 0.f ? v0 : 0.f;
            float v1 = acc11[r] + b1; v1 = v1 > 0.f ? v1 : 0.f;
            if (mode == 0) {
                Cbf[(size_t)row2 * HID + colb]      = f2bf(v0);
                Cbf[(size_t)row2 * HID + colb + 16] = f2bf(v1);
            } else {
                Cf[(size_t)row2 * HID + colb]      = v0;
                Cf[(size_t)row2 * HID + colb + 16] = v1;
            }
        }
    }
}

// ---------------- launch ----------------

extern "C" void kernel_launch(void* const* d_in, const int* in_sizes, int n_in,
                              void* d_out, int out_size, void* d_ws, size_t ws_size,
                              hipStream_t stream) {
    const float* x  = (const float*)d_in[0];
    const int*   ei = (const int*)d_in[1];
    const float* ew = (const float*)d_in[2];
    const float* W1 = (const float*)d_in[3];
    const float* b1 = (const float*)d_in[4];
    const float* W2 = (const float*)d_in[5];
    const float* b2 = (const float*)d_in[6];
    float* out = (float*)d_out;

    char* ws = (char*)d_ws;
    float* deg      = (float*)(ws);                 // 20000 f32 (becomes dinv)
    int*   counts   = (int*)(ws + 80000);           // 20000 i32
    int*   cursor   = (int*)(ws + 160000);          // 20000 i32
    int*   offs     = (int*)(ws + 240000);          // 20001 i32 -> 320004 (pad 320016)
    int*   bsum     = (int*)(ws + 320016);          // 20 i32 -> 320096 (pad 320144)
    int2*  er       = (int2*)(ws + 320144);         // 480000 int2 (8-padded buckets) -> 4160144
    // region A: ax (20000x192 bf16, 7.68MB) dead after gemm1; reused for ah
    short* ax       = (short*)(ws + 4160144);       // -> 11840144
    short* ah       = (short*)(ws + 4160144);       // 20000x256 -> 14400144
    short* h1h      = (short*)(ws + 14400144);      // 20000x256 bf16 -> 24640144
    short* w1b      = (short*)(ws + 24640144);      // 256x192 -> 24738448
    short* w2b      = (short*)(ws + 24738448);      // 256x256 -> 24869520
    short* xb       = (short*)(ws + 24869520);      // 20000x192 bf16 -> 32549520

    // zero deg/counts/cursor/offs/bsum only; er pad slots are written explicitly
    hipMemsetAsync(d_ws, 0, 320144, stream);

    const int prep_tot = N_NODES * X4 + 256 * X4 + 256 * 64 + N_EDGES; // 1308672
    prep_all<<<(prep_tot + 255) / 256, 256, 0, stream>>>(
        x, xb, W1, W2, w1b, w2b, ei, ew, deg, counts);
    scan_part<<<20, 1024, 0, stream>>>(counts, offs, bsum, deg, N_NODES);
    scan_add<<<20, 1024, 0, stream>>>(bsum, offs, N_NODES);
    // edge scatter + explicit pad-slot zero-fill in one dispatch
    const int sc_blocks = (N_EDGES + N_NODES + 255) / 256;  // 1329
    scatter_edges<<<sc_blocks, 256, 0, stream>>>(ei, ew, deg, offs, counts, cursor, er);

    const int mtiles = (N_NODES + 63) / 64;          // 313
    const int gemm_grid = ((mtiles + 7) / 8) * 32;   // 1280
    // layer 1: Agg(bf16 xb) -> bf16; GEMM(+b1, ReLU) -> h1 bf16
    agg_x<<<N_NODES / 4, 256, 0, stream>>>(xb, deg, offs, er, ax);
    gemm_bf<<<gemm_grid, 256, 0, stream>>>(ax, w1b, b1, nullptr, h1h,
                                           N_NODES, K1P, 3, 0);
    // layer 2: Agg(bf16 h1) -> bf16; GEMM(+b2, ReLU) -> out fp32
    agg_h<<<N_NODES / 4, 256, 0, stream>>>(h1h, deg, offs, er, ah);
    gemm_bf<<<gemm_grid, 256, 0, stream>>>(ah, w2b, b2, out, nullptr,
                                           N_NODES, HID, 4, 1);
}